// Round 1
// baseline (1443.295 us; speedup 1.0000x reference)
//
#include <hip/hip_runtime.h>

#define HIDDEN 128
#define LEAKY 0.01f

// Stage 1: per-node attention scores s_i = x @ w_i, s_j = x @ w_j.
// One 64-lane wave per node; lane l handles features [2l, 2l+1].
__global__ void node_scores_k(const float* __restrict__ x,
                              const float* __restrict__ w_i,
                              const float* __restrict__ w_j,
                              float* __restrict__ s_i,
                              float* __restrict__ s_j,
                              int n_nodes) {
    int gtid = blockIdx.x * blockDim.x + threadIdx.x;
    int node = gtid >> 6;
    int lane = threadIdx.x & 63;
    if (node >= n_nodes) return;
    const float2* xr = reinterpret_cast<const float2*>(x + (size_t)node * HIDDEN);
    float2 xv = xr[lane];
    float2 wi = reinterpret_cast<const float2*>(w_i)[lane];
    float2 wj = reinterpret_cast<const float2*>(w_j)[lane];
    float di = xv.x * wi.x + xv.y * wi.y;
    float dj = xv.x * wj.x + xv.y * wj.y;
    #pragma unroll
    for (int off = 32; off > 0; off >>= 1) {
        di += __shfl_xor(di, off, 64);
        dj += __shfl_xor(dj, off, 64);
    }
    if (lane == 0) {
        s_i[node] = di;
        s_j[node] = dj;
    }
}

// Stage 2: per-edge e = leaky_relu(s_i[h] + s_j[t]); ex = exp(e)
// (softmax is shift-invariant; e is O(+-10) here so no max-subtraction needed),
// accumulate segment sums by source node h.
__global__ void edge_exp_k(const float* __restrict__ s_i,
                           const float* __restrict__ s_j,
                           const int* __restrict__ h,
                           const int* __restrict__ t,
                           float* __restrict__ ex,
                           float* __restrict__ seg_sum,
                           int n_edges) {
    int i = blockIdx.x * blockDim.x + threadIdx.x;
    if (i >= n_edges) return;
    int hh = h[i];
    float e = s_i[hh] + s_j[t[i]];
    e = e > 0.0f ? e : LEAKY * e;
    float v = expf(e);
    ex[i] = v;
    atomicAdd(&seg_sum[hh], v);
}

// Stage 3: out[h[e]] += (ex[e]/seg_sum[h[e]]) * x[t[e]].
// One wave per edge; lane l does features [2l, 2l+1] via fp32 atomics
// (coalesced 512B burst per edge into the L2/L3-resident out buffer).
__global__ void aggregate_k(const float* __restrict__ x,
                            const int* __restrict__ h,
                            const int* __restrict__ t,
                            const float* __restrict__ ex,
                            const float* __restrict__ seg_sum,
                            float* __restrict__ out,
                            int n_edges) {
    int gtid = blockIdx.x * blockDim.x + threadIdx.x;
    int edge = gtid >> 6;
    int lane = threadIdx.x & 63;
    if (edge >= n_edges) return;
    int hh = h[edge];
    int tt = t[edge];
    float alpha = ex[edge] / seg_sum[hh];
    const float2* xr = reinterpret_cast<const float2*>(x + (size_t)tt * HIDDEN);
    float2 xv = xr[lane];
    float* op = out + (size_t)hh * HIDDEN + 2 * lane;
    atomicAdd(op,     alpha * xv.x);
    atomicAdd(op + 1, alpha * xv.y);
}

// Stage 4: in-place ReLU on out.
__global__ void relu_k(float* __restrict__ out, int n) {
    int i = blockIdx.x * blockDim.x + threadIdx.x;
    if (i < n) {
        float v = out[i];
        out[i] = v > 0.0f ? v : 0.0f;
    }
}

extern "C" void kernel_launch(void* const* d_in, const int* in_sizes, int n_in,
                              void* d_out, int out_size, void* d_ws, size_t ws_size,
                              hipStream_t stream) {
    const float* x   = (const float*)d_in[0];
    const float* w_i = (const float*)d_in[1];
    const float* w_j = (const float*)d_in[2];
    const int*   h   = (const int*)d_in[3];
    const int*   t   = (const int*)d_in[4];
    float* out = (float*)d_out;

    const int n_nodes = in_sizes[0] / HIDDEN;
    const int n_edges = in_sizes[3];

    // Workspace layout (floats): s_i[N] | s_j[N] | seg_sum[N] | ex[E]
    float* s_i     = (float*)d_ws;
    float* s_j     = s_i + n_nodes;
    float* seg_sum = s_j + n_nodes;
    float* ex      = seg_sum + n_nodes;

    // Zero accumulators (graph-capture-safe async memset on stream).
    hipMemsetAsync(d_out, 0, (size_t)out_size * sizeof(float), stream);
    hipMemsetAsync(seg_sum, 0, (size_t)n_nodes * sizeof(float), stream);

    {   // Stage 1: one wave per node, 256-thread blocks = 4 waves/block.
        int waves_per_block = 256 / 64;
        int blocks = (n_nodes + waves_per_block - 1) / waves_per_block;
        node_scores_k<<<blocks, 256, 0, stream>>>(x, w_i, w_j, s_i, s_j, n_nodes);
    }
    {   // Stage 2: thread per edge.
        int blocks = (n_edges + 255) / 256;
        edge_exp_k<<<blocks, 256, 0, stream>>>(s_i, s_j, h, t, ex, seg_sum, n_edges);
    }
    {   // Stage 3: wave per edge.
        int waves_per_block = 256 / 64;
        int blocks = (n_edges + waves_per_block - 1) / waves_per_block;
        aggregate_k<<<blocks, 256, 0, stream>>>(x, h, t, ex, seg_sum, out, n_edges);
    }
    {   // Stage 4: elementwise ReLU.
        int blocks = (out_size + 255) / 256;
        relu_k<<<blocks, 256, 0, stream>>>(out, out_size);
    }
}

// Round 2
// 342.143 us; speedup vs baseline: 4.2184x; 4.2184x over previous
//
#include <hip/hip_runtime.h>

#define HIDDEN 128
#define LEAKY 0.01f
#define SCAN_CHUNK 1024  // 256 threads * 4 elems

// ---------------- Stage 1: per-node scores s_i = x@w_i, s_j = x@w_j ----------
__global__ void node_scores_k(const float* __restrict__ x,
                              const float* __restrict__ w_i,
                              const float* __restrict__ w_j,
                              float* __restrict__ s_i,
                              float* __restrict__ s_j,
                              int n_nodes) {
    int gtid = blockIdx.x * blockDim.x + threadIdx.x;
    int node = gtid >> 6;
    int lane = threadIdx.x & 63;
    if (node >= n_nodes) return;
    const float2* xr = reinterpret_cast<const float2*>(x + (size_t)node * HIDDEN);
    float2 xv = xr[lane];
    float2 wi = reinterpret_cast<const float2*>(w_i)[lane];
    float2 wj = reinterpret_cast<const float2*>(w_j)[lane];
    float di = xv.x * wi.x + xv.y * wi.y;
    float dj = xv.x * wj.x + xv.y * wj.y;
    #pragma unroll
    for (int off = 32; off > 0; off >>= 1) {
        di += __shfl_xor(di, off, 64);
        dj += __shfl_xor(dj, off, 64);
    }
    if (lane == 0) {
        s_i[node] = di;
        s_j[node] = dj;
    }
}

// ---------------- Stage 2: histogram of h ------------------------------------
__global__ void hist_k(const int* __restrict__ h, int* __restrict__ counts,
                       int n_edges) {
    int i = blockIdx.x * blockDim.x + threadIdx.x;
    if (i < n_edges) atomicAdd(&counts[h[i]], 1);
}

// ---------------- Stage 3: exclusive scan of counts -> offsets ---------------
// 3a: per-chunk scan (1024 elems per 256-thread block), chunk totals out.
__global__ void scan1_k(const int* __restrict__ counts, int* __restrict__ offsets,
                        int* __restrict__ blockSums, int n) {
    __shared__ int lds[256];
    int tid = threadIdx.x;
    int base = blockIdx.x * SCAN_CHUNK + tid * 4;
    int v0 = (base + 0 < n) ? counts[base + 0] : 0;
    int v1 = (base + 1 < n) ? counts[base + 1] : 0;
    int v2 = (base + 2 < n) ? counts[base + 2] : 0;
    int v3 = (base + 3 < n) ? counts[base + 3] : 0;
    int tsum = v0 + v1 + v2 + v3;
    lds[tid] = tsum;
    __syncthreads();
    for (int off = 1; off < 256; off <<= 1) {
        int addend = (tid >= off) ? lds[tid - off] : 0;
        __syncthreads();
        if (tid >= off) lds[tid] += addend;
        __syncthreads();
    }
    int incl = lds[tid];
    int excl = incl - tsum;
    if (tid == 255) blockSums[blockIdx.x] = incl;
    int run = excl;
    if (base + 0 < n) { offsets[base + 0] = run; } run += v0;
    if (base + 1 < n) { offsets[base + 1] = run; } run += v1;
    if (base + 2 < n) { offsets[base + 2] = run; } run += v2;
    if (base + 3 < n) { offsets[base + 3] = run; }
}

// 3b: scan the chunk totals (single block; nblocks <= 256).
__global__ void scan2_k(int* __restrict__ blockSums, int nblocks) {
    __shared__ int lds[256];
    int tid = threadIdx.x;
    int v = (tid < nblocks) ? blockSums[tid] : 0;
    lds[tid] = v;
    __syncthreads();
    for (int off = 1; off < 256; off <<= 1) {
        int addend = (tid >= off) ? lds[tid - off] : 0;
        __syncthreads();
        if (tid >= off) lds[tid] += addend;
        __syncthreads();
    }
    if (tid < nblocks) blockSums[tid] = lds[tid] - v;  // exclusive
}

// 3c: add chunk bases back.
__global__ void scan3_k(int* __restrict__ offsets, const int* __restrict__ blockSums,
                        int n) {
    int base = blockIdx.x * SCAN_CHUNK + threadIdx.x * 4;
    int add = blockSums[blockIdx.x];
    if (base + 0 < n) offsets[base + 0] += add;
    if (base + 1 < n) offsets[base + 1] += add;
    if (base + 2 < n) offsets[base + 2] += add;
    if (base + 3 < n) offsets[base + 3] += add;
}

// ---------------- Stage 4: scatter edges into CSR order, compute ex ----------
__global__ void scatter_k(const float* __restrict__ s_i,
                          const float* __restrict__ s_j,
                          const int* __restrict__ h,
                          const int* __restrict__ t,
                          const int* __restrict__ offsets,
                          int* __restrict__ cursors,
                          int* __restrict__ t_sorted,
                          float* __restrict__ ex_sorted,
                          int n_edges) {
    int i = blockIdx.x * blockDim.x + threadIdx.x;
    if (i >= n_edges) return;
    int hh = h[i];
    int tt = t[i];
    float e = s_i[hh] + s_j[tt];
    e = e > 0.0f ? e : LEAKY * e;
    float ex = expf(e);   // softmax is shift-invariant; e is O(+-10), no max pass
    int pos = offsets[hh] + atomicAdd(&cursors[hh], 1);
    t_sorted[pos] = tt;
    ex_sorted[pos] = ex;
}

// ---------------- Stage 5: per-node aggregation, fused ReLU ------------------
// One wave per node. Phase 1: in-register segment sum of ex (contiguous).
// Phase 2: acc[128] (float2/lane) += alpha * x[t]; single coalesced store.
__global__ void aggregate_k(const float* __restrict__ x,
                            const int* __restrict__ offsets,
                            const int* __restrict__ counts,
                            const int* __restrict__ t_sorted,
                            const float* __restrict__ ex_sorted,
                            float* __restrict__ out,
                            int n_nodes) {
    int gtid = blockIdx.x * blockDim.x + threadIdx.x;
    int node = gtid >> 6;
    int lane = threadIdx.x & 63;
    if (node >= n_nodes) return;
    int beg = offsets[node];
    int deg = counts[node];
    int end = beg + deg;

    // Phase 1: segment sum of ex over [beg, end) — contiguous, strided by lane.
    float ssum = 0.0f;
    for (int j = beg + lane; j < end; j += 64) ssum += ex_sorted[j];
    #pragma unroll
    for (int off = 32; off > 0; off >>= 1) ssum += __shfl_xor(ssum, off, 64);
    float inv = (deg > 0) ? (1.0f / ssum) : 0.0f;

    // Phase 2: weighted row accumulation.
    float accx = 0.0f, accy = 0.0f;
    for (int j = beg; j < end; ++j) {
        float a = ex_sorted[j] * inv;           // wave-uniform broadcast load
        int tt = t_sorted[j];                   // wave-uniform broadcast load
        float2 xv = reinterpret_cast<const float2*>(x + (size_t)tt * HIDDEN)[lane];
        accx += a * xv.x;
        accy += a * xv.y;
    }
    float2 o;
    o.x = accx > 0.0f ? accx : 0.0f;            // fused ReLU
    o.y = accy > 0.0f ? accy : 0.0f;
    reinterpret_cast<float2*>(out + (size_t)node * HIDDEN)[lane] = o;
}

extern "C" void kernel_launch(void* const* d_in, const int* in_sizes, int n_in,
                              void* d_out, int out_size, void* d_ws, size_t ws_size,
                              hipStream_t stream) {
    const float* x   = (const float*)d_in[0];
    const float* w_i = (const float*)d_in[1];
    const float* w_j = (const float*)d_in[2];
    const int*   h   = (const int*)d_in[3];
    const int*   t   = (const int*)d_in[4];
    float* out = (float*)d_out;

    const int n_nodes = in_sizes[0] / HIDDEN;
    const int n_edges = in_sizes[3];
    const int nchunks = (n_nodes + SCAN_CHUNK - 1) / SCAN_CHUNK;  // <= 256

    // Workspace layout:
    // s_i[N] f | s_j[N] f | counts[N] i | offsets[N] i | cursors[N] i |
    // blockSums[256] i | t_sorted[E] i | ex_sorted[E] f
    float* s_i     = (float*)d_ws;
    float* s_j     = s_i + n_nodes;
    int*   counts  = (int*)(s_j + n_nodes);
    int*   offsets = counts + n_nodes;
    int*   cursors = offsets + n_nodes;
    int*   blockSums = cursors + n_nodes;
    int*   t_sorted  = blockSums + 256;
    float* ex_sorted = (float*)(t_sorted + n_edges);

    hipMemsetAsync(counts, 0, (size_t)n_nodes * sizeof(int), stream);
    hipMemsetAsync(cursors, 0, (size_t)n_nodes * sizeof(int), stream);

    {   // Stage 1: wave per node.
        int blocks = (n_nodes * 64 + 255) / 256;
        node_scores_k<<<blocks, 256, 0, stream>>>(x, w_i, w_j, s_i, s_j, n_nodes);
    }
    {   // Stage 2: histogram.
        int blocks = (n_edges + 255) / 256;
        hist_k<<<blocks, 256, 0, stream>>>(h, counts, n_edges);
    }
    {   // Stage 3: exclusive scan counts -> offsets.
        scan1_k<<<nchunks, 256, 0, stream>>>(counts, offsets, blockSums, n_nodes);
        scan2_k<<<1, 256, 0, stream>>>(blockSums, nchunks);
        scan3_k<<<nchunks, 256, 0, stream>>>(offsets, blockSums, n_nodes);
    }
    {   // Stage 4: scatter into CSR order.
        int blocks = (n_edges + 255) / 256;
        scatter_k<<<blocks, 256, 0, stream>>>(s_i, s_j, h, t, offsets, cursors,
                                              t_sorted, ex_sorted, n_edges);
    }
    {   // Stage 5: aggregate + ReLU, wave per node.
        int blocks = (n_nodes * 64 + 255) / 256;
        aggregate_k<<<blocks, 256, 0, stream>>>(x, offsets, counts, t_sorted,
                                                ex_sorted, out, n_nodes);
    }
}

// Round 3
// 285.658 us; speedup vs baseline: 5.0525x; 1.1977x over previous
//
#include <hip/hip_runtime.h>
#include <string.h>

#define HIDDEN 128
#define LEAKY 0.01f
#define SCAN_CHUNK 1024  // 256 threads * 4 elems

// ---------------- Stage 1: per-node scores s_i = x@w_i, s_j = x@w_j ----------
__global__ void node_scores_k(const float* __restrict__ x,
                              const float* __restrict__ w_i,
                              const float* __restrict__ w_j,
                              float* __restrict__ s_i,
                              float* __restrict__ s_j,
                              int n_nodes) {
    int gtid = blockIdx.x * blockDim.x + threadIdx.x;
    int node = gtid >> 6;
    int lane = threadIdx.x & 63;
    if (node >= n_nodes) return;
    const float2* xr = reinterpret_cast<const float2*>(x + (size_t)node * HIDDEN);
    float2 xv = xr[lane];
    float2 wi = reinterpret_cast<const float2*>(w_i)[lane];
    float2 wj = reinterpret_cast<const float2*>(w_j)[lane];
    float di = xv.x * wi.x + xv.y * wi.y;
    float dj = xv.x * wj.x + xv.y * wj.y;
    #pragma unroll
    for (int off = 32; off > 0; off >>= 1) {
        di += __shfl_xor(di, off, 64);
        dj += __shfl_xor(dj, off, 64);
    }
    if (lane == 0) {
        s_i[node] = di;
        s_j[node] = dj;
    }
}

// ---------------- Stage 2: histogram of h ------------------------------------
__global__ void hist_k(const int* __restrict__ h, int* __restrict__ counts,
                       int n_edges) {
    int i = blockIdx.x * blockDim.x + threadIdx.x;
    if (i < n_edges) atomicAdd(&counts[h[i]], 1);
}

// ---------------- Stage 3: exclusive scan of counts -> offsets ---------------
__global__ void scan1_k(const int* __restrict__ counts, int* __restrict__ offsets,
                        int* __restrict__ blockSums, int n) {
    __shared__ int lds[256];
    int tid = threadIdx.x;
    int base = blockIdx.x * SCAN_CHUNK + tid * 4;
    int v0 = (base + 0 < n) ? counts[base + 0] : 0;
    int v1 = (base + 1 < n) ? counts[base + 1] : 0;
    int v2 = (base + 2 < n) ? counts[base + 2] : 0;
    int v3 = (base + 3 < n) ? counts[base + 3] : 0;
    int tsum = v0 + v1 + v2 + v3;
    lds[tid] = tsum;
    __syncthreads();
    for (int off = 1; off < 256; off <<= 1) {
        int addend = (tid >= off) ? lds[tid - off] : 0;
        __syncthreads();
        if (tid >= off) lds[tid] += addend;
        __syncthreads();
    }
    int incl = lds[tid];
    int excl = incl - tsum;
    if (tid == 255) blockSums[blockIdx.x] = incl;
    int run = excl;
    if (base + 0 < n) { offsets[base + 0] = run; } run += v0;
    if (base + 1 < n) { offsets[base + 1] = run; } run += v1;
    if (base + 2 < n) { offsets[base + 2] = run; } run += v2;
    if (base + 3 < n) { offsets[base + 3] = run; }
}

__global__ void scan2_k(int* __restrict__ blockSums, int nblocks) {
    __shared__ int lds[256];
    int tid = threadIdx.x;
    int v = (tid < nblocks) ? blockSums[tid] : 0;
    lds[tid] = v;
    __syncthreads();
    for (int off = 1; off < 256; off <<= 1) {
        int addend = (tid >= off) ? lds[tid - off] : 0;
        __syncthreads();
        if (tid >= off) lds[tid] += addend;
        __syncthreads();
    }
    if (tid < nblocks) blockSums[tid] = lds[tid] - v;  // exclusive
}

__global__ void scan3_k(int* __restrict__ offsets, const int* __restrict__ blockSums,
                        int n) {
    int base = blockIdx.x * SCAN_CHUNK + threadIdx.x * 4;
    int add = blockSums[blockIdx.x];
    if (base + 0 < n) offsets[base + 0] += add;
    if (base + 1 < n) offsets[base + 1] += add;
    if (base + 2 < n) offsets[base + 2] += add;
    if (base + 3 < n) offsets[base + 3] += add;
}

// ---------------- Stage 4: scatter edges into CSR order ----------------------
// One combined 8B {t, ex} store per edge (half the random lines of two arrays).
__global__ void scatter_k(const float* __restrict__ s_i,
                          const float* __restrict__ s_j,
                          const int* __restrict__ h,
                          const int* __restrict__ t,
                          const int* __restrict__ offsets,
                          int* __restrict__ cursors,
                          int2* __restrict__ te_sorted,
                          int n_edges) {
    int i = blockIdx.x * blockDim.x + threadIdx.x;
    if (i >= n_edges) return;
    int hh = h[i];
    int tt = t[i];
    float e = s_i[hh] + s_j[tt];
    e = e > 0.0f ? e : LEAKY * e;
    float ex = expf(e);   // softmax is shift-invariant; e is O(+-10), no max pass
    int pos = offsets[hh] + atomicAdd(&cursors[hh], 1);
    int2 te;
    te.x = tt;
    te.y = __float_as_int(ex);
    te_sorted[pos] = te;
}

// ---------------- Stage 5: single-pass per-node aggregation, fused ReLU ------
// One wave per node. Every lane walks every edge, so each lane's local sum of
// ex equals the full segment sum (no shuffle reduce, no separate pass):
//   out = relu( (sum_j ex_j * x[t_j]) / sum_j ex_j )
// Unroll x4 -> 4 concurrent 512B row-gathers per wave (MLP).
__global__ void aggregate_k(const float* __restrict__ x,
                            const int* __restrict__ offsets,
                            const int* __restrict__ counts,
                            const int2* __restrict__ te_sorted,
                            float* __restrict__ out,
                            int n_nodes) {
    int gtid = blockIdx.x * blockDim.x + threadIdx.x;
    int node = gtid >> 6;
    int lane = threadIdx.x & 63;
    if (node >= n_nodes) return;
    int beg = offsets[node];
    int deg = counts[node];
    int end = beg + deg;

    float accx = 0.0f, accy = 0.0f, ssum = 0.0f;
    int j = beg;
    for (; j + 4 <= end; j += 4) {
        int2 e0 = te_sorted[j + 0];
        int2 e1 = te_sorted[j + 1];
        int2 e2 = te_sorted[j + 2];
        int2 e3 = te_sorted[j + 3];
        float2 v0 = reinterpret_cast<const float2*>(x + (size_t)e0.x * HIDDEN)[lane];
        float2 v1 = reinterpret_cast<const float2*>(x + (size_t)e1.x * HIDDEN)[lane];
        float2 v2 = reinterpret_cast<const float2*>(x + (size_t)e2.x * HIDDEN)[lane];
        float2 v3 = reinterpret_cast<const float2*>(x + (size_t)e3.x * HIDDEN)[lane];
        float a0 = __int_as_float(e0.y);
        float a1 = __int_as_float(e1.y);
        float a2 = __int_as_float(e2.y);
        float a3 = __int_as_float(e3.y);
        ssum += (a0 + a1) + (a2 + a3);
        accx += a0 * v0.x + a1 * v1.x + a2 * v2.x + a3 * v3.x;
        accy += a0 * v0.y + a1 * v1.y + a2 * v2.y + a3 * v3.y;
    }
    for (; j < end; ++j) {
        int2 e0 = te_sorted[j];
        float2 v0 = reinterpret_cast<const float2*>(x + (size_t)e0.x * HIDDEN)[lane];
        float a0 = __int_as_float(e0.y);
        ssum += a0;
        accx += a0 * v0.x;
        accy += a0 * v0.y;
    }

    float inv = (deg > 0) ? (1.0f / ssum) : 0.0f;
    float ox = accx * inv;
    float oy = accy * inv;
    float2 o;
    o.x = ox > 0.0f ? ox : 0.0f;   // fused ReLU
    o.y = oy > 0.0f ? oy : 0.0f;
    // Nontemporal store: don't let the 51MB streaming write evict x from L2/L3.
    long long bits;
    memcpy(&bits, &o, 8);
    long long* dst = reinterpret_cast<long long*>(out + (size_t)node * HIDDEN) + lane;
    __builtin_nontemporal_store(bits, dst);
}

extern "C" void kernel_launch(void* const* d_in, const int* in_sizes, int n_in,
                              void* d_out, int out_size, void* d_ws, size_t ws_size,
                              hipStream_t stream) {
    const float* x   = (const float*)d_in[0];
    const float* w_i = (const float*)d_in[1];
    const float* w_j = (const float*)d_in[2];
    const int*   h   = (const int*)d_in[3];
    const int*   t   = (const int*)d_in[4];
    float* out = (float*)d_out;

    const int n_nodes = in_sizes[0] / HIDDEN;
    const int n_edges = in_sizes[3];
    const int nchunks = (n_nodes + SCAN_CHUNK - 1) / SCAN_CHUNK;  // <= 256

    // Workspace layout:
    // s_i[N] f | s_j[N] f | counts[N] i | offsets[N] i | cursors[N] i |
    // blockSums[256] i | te_sorted[E] int2
    float* s_i       = (float*)d_ws;
    float* s_j       = s_i + n_nodes;
    int*   counts    = (int*)(s_j + n_nodes);
    int*   offsets   = counts + n_nodes;
    int*   cursors   = offsets + n_nodes;
    int*   blockSums = cursors + n_nodes;
    int2*  te_sorted = reinterpret_cast<int2*>(blockSums + 256);

    hipMemsetAsync(counts, 0, (size_t)n_nodes * sizeof(int), stream);
    hipMemsetAsync(cursors, 0, (size_t)n_nodes * sizeof(int), stream);

    {   // Stage 1: wave per node.
        int blocks = (n_nodes * 64 + 255) / 256;
        node_scores_k<<<blocks, 256, 0, stream>>>(x, w_i, w_j, s_i, s_j, n_nodes);
    }
    {   // Stage 2: histogram.
        int blocks = (n_edges + 255) / 256;
        hist_k<<<blocks, 256, 0, stream>>>(h, counts, n_edges);
    }
    {   // Stage 3: exclusive scan counts -> offsets.
        scan1_k<<<nchunks, 256, 0, stream>>>(counts, offsets, blockSums, n_nodes);
        scan2_k<<<1, 256, 0, stream>>>(blockSums, nchunks);
        scan3_k<<<nchunks, 256, 0, stream>>>(offsets, blockSums, n_nodes);
    }
    {   // Stage 4: scatter into CSR order.
        int blocks = (n_edges + 255) / 256;
        scatter_k<<<blocks, 256, 0, stream>>>(s_i, s_j, h, t, offsets, cursors,
                                              te_sorted, n_edges);
    }
    {   // Stage 5: single-pass aggregate + ReLU, wave per node.
        int blocks = (n_nodes * 64 + 255) / 256;
        aggregate_k<<<blocks, 256, 0, stream>>>(x, offsets, counts, te_sorted,
                                                out, n_nodes);
    }
}

// Round 4
// 274.622 us; speedup vs baseline: 5.2556x; 1.0402x over previous
//
#include <hip/hip_runtime.h>
#include <string.h>

#define HIDDEN 128
#define LEAKY 0.01f
#define SCAN_CHUNK 1024  // 256 threads * 4 elems

// ---------------- Stage 0: fp32 -> bf16 copy of x (RNE) ----------------------
// Halves the per-edge gather payload in aggregate (256B/row vs 512B).
__device__ __forceinline__ unsigned int rne_bf16(float f) {
    unsigned int x = __float_as_uint(f);
    return (x + 0x7FFFu + ((x >> 16) & 1u)) >> 16;
}

__global__ void cvt_bf16_k(const float* __restrict__ x,
                           unsigned short* __restrict__ xb, long long n) {
    long long i = (long long)(blockIdx.x * blockDim.x + threadIdx.x) * 4;
    if (i >= n) return;
    float4 v = *reinterpret_cast<const float4*>(x + i);
    unsigned int p0 = rne_bf16(v.x) | (rne_bf16(v.y) << 16);
    unsigned int p1 = rne_bf16(v.z) | (rne_bf16(v.w) << 16);
    uint2 p; p.x = p0; p.y = p1;
    *reinterpret_cast<uint2*>(xb + i) = p;
}

// ---------------- Stage 1: per-node scores s_i = x@w_i, s_j = x@w_j ----------
__global__ void node_scores_k(const float* __restrict__ x,
                              const float* __restrict__ w_i,
                              const float* __restrict__ w_j,
                              float* __restrict__ s_i,
                              float* __restrict__ s_j,
                              int n_nodes) {
    int gtid = blockIdx.x * blockDim.x + threadIdx.x;
    int node = gtid >> 6;
    int lane = threadIdx.x & 63;
    if (node >= n_nodes) return;
    const float2* xr = reinterpret_cast<const float2*>(x + (size_t)node * HIDDEN);
    float2 xv = xr[lane];
    float2 wi = reinterpret_cast<const float2*>(w_i)[lane];
    float2 wj = reinterpret_cast<const float2*>(w_j)[lane];
    float di = xv.x * wi.x + xv.y * wi.y;
    float dj = xv.x * wj.x + xv.y * wj.y;
    #pragma unroll
    for (int off = 32; off > 0; off >>= 1) {
        di += __shfl_xor(di, off, 64);
        dj += __shfl_xor(dj, off, 64);
    }
    if (lane == 0) {
        s_i[node] = di;
        s_j[node] = dj;
    }
}

// ---------------- Stage 2: histogram of h ------------------------------------
__global__ void hist_k(const int* __restrict__ h, int* __restrict__ counts,
                       int n_edges) {
    int i = blockIdx.x * blockDim.x + threadIdx.x;
    if (i < n_edges) atomicAdd(&counts[h[i]], 1);
}

// ---------------- Stage 3: exclusive scan of counts -> offsets ---------------
__global__ void scan1_k(const int* __restrict__ counts, int* __restrict__ offsets,
                        int* __restrict__ blockSums, int n) {
    __shared__ int lds[256];
    int tid = threadIdx.x;
    int base = blockIdx.x * SCAN_CHUNK + tid * 4;
    int v0 = (base + 0 < n) ? counts[base + 0] : 0;
    int v1 = (base + 1 < n) ? counts[base + 1] : 0;
    int v2 = (base + 2 < n) ? counts[base + 2] : 0;
    int v3 = (base + 3 < n) ? counts[base + 3] : 0;
    int tsum = v0 + v1 + v2 + v3;
    lds[tid] = tsum;
    __syncthreads();
    for (int off = 1; off < 256; off <<= 1) {
        int addend = (tid >= off) ? lds[tid - off] : 0;
        __syncthreads();
        if (tid >= off) lds[tid] += addend;
        __syncthreads();
    }
    int incl = lds[tid];
    int excl = incl - tsum;
    if (tid == 255) blockSums[blockIdx.x] = incl;
    int run = excl;
    if (base + 0 < n) { offsets[base + 0] = run; } run += v0;
    if (base + 1 < n) { offsets[base + 1] = run; } run += v1;
    if (base + 2 < n) { offsets[base + 2] = run; } run += v2;
    if (base + 3 < n) { offsets[base + 3] = run; }
}

__global__ void scan2_k(int* __restrict__ blockSums, int nblocks) {
    __shared__ int lds[256];
    int tid = threadIdx.x;
    int v = (tid < nblocks) ? blockSums[tid] : 0;
    lds[tid] = v;
    __syncthreads();
    for (int off = 1; off < 256; off <<= 1) {
        int addend = (tid >= off) ? lds[tid - off] : 0;
        __syncthreads();
        if (tid >= off) lds[tid] += addend;
        __syncthreads();
    }
    if (tid < nblocks) blockSums[tid] = lds[tid] - v;  // exclusive
}

__global__ void scan3_k(int* __restrict__ offsets, const int* __restrict__ blockSums,
                        int n) {
    int base = blockIdx.x * SCAN_CHUNK + threadIdx.x * 4;
    int add = blockSums[blockIdx.x];
    if (base + 0 < n) offsets[base + 0] += add;
    if (base + 1 < n) offsets[base + 1] += add;
    if (base + 2 < n) offsets[base + 2] += add;
    if (base + 3 < n) offsets[base + 3] += add;
}

// ---------------- Stage 4: scatter edges into CSR order ----------------------
__global__ void scatter_k(const float* __restrict__ s_i,
                          const float* __restrict__ s_j,
                          const int* __restrict__ h,
                          const int* __restrict__ t,
                          const int* __restrict__ offsets,
                          int* __restrict__ cursors,
                          int2* __restrict__ te_sorted,
                          int n_edges) {
    int i = blockIdx.x * blockDim.x + threadIdx.x;
    if (i >= n_edges) return;
    int hh = h[i];
    int tt = t[i];
    float e = s_i[hh] + s_j[tt];
    e = e > 0.0f ? e : LEAKY * e;
    float ex = expf(e);   // softmax is shift-invariant; e is O(+-10), no max pass
    int pos = offsets[hh] + atomicAdd(&cursors[hh], 1);
    int2 te;
    te.x = tt;
    te.y = __float_as_int(ex);
    te_sorted[pos] = te;
}

// ---------------- Stage 5: single-pass per-node aggregation, fused ReLU ------
// One wave per node; bf16 x gathers (256B/row); unroll x8 for MLP.
// Every lane walks every edge, so each lane's local sum of ex equals the
// full segment sum: out = relu( (sum_j ex_j * x[t_j]) / sum_j ex_j ).
__global__ void aggregate_bf16_k(const unsigned short* __restrict__ xb,
                                 const int* __restrict__ offsets,
                                 const int* __restrict__ counts,
                                 const long long* __restrict__ te_sorted,
                                 float* __restrict__ out,
                                 int n_nodes) {
    int gtid = blockIdx.x * blockDim.x + threadIdx.x;
    int node = gtid >> 6;
    int lane = threadIdx.x & 63;
    if (node >= n_nodes) return;
    int beg = offsets[node];
    int deg = counts[node];
    int end = beg + deg;

    float accx = 0.0f, accy = 0.0f, ssum = 0.0f;
    int j = beg;
    #define LOAD_EDGE(K, JJ)                                                     \
        long long te##K = __builtin_nontemporal_load(te_sorted + (JJ));          \
        unsigned int u##K = *reinterpret_cast<const unsigned int*>(              \
            xb + (size_t)(int)te##K * HIDDEN + 2 * lane);
    #define ACC_EDGE(K)                                                          \
        {                                                                        \
            float a = __int_as_float((int)(te##K >> 32));                        \
            float fx = __uint_as_float(u##K << 16);                              \
            float fy = __uint_as_float(u##K & 0xFFFF0000u);                      \
            ssum += a;                                                           \
            accx += a * fx;                                                      \
            accy += a * fy;                                                      \
        }
    for (; j + 8 <= end; j += 8) {
        LOAD_EDGE(0, j + 0) LOAD_EDGE(1, j + 1) LOAD_EDGE(2, j + 2)
        LOAD_EDGE(3, j + 3) LOAD_EDGE(4, j + 4) LOAD_EDGE(5, j + 5)
        LOAD_EDGE(6, j + 6) LOAD_EDGE(7, j + 7)
        ACC_EDGE(0) ACC_EDGE(1) ACC_EDGE(2) ACC_EDGE(3)
        ACC_EDGE(4) ACC_EDGE(5) ACC_EDGE(6) ACC_EDGE(7)
    }
    for (; j < end; ++j) {
        LOAD_EDGE(9, j)
        ACC_EDGE(9)
    }
    #undef LOAD_EDGE
    #undef ACC_EDGE

    float inv = (deg > 0) ? (1.0f / ssum) : 0.0f;
    float ox = accx * inv;
    float oy = accy * inv;
    float2 o;
    o.x = ox > 0.0f ? ox : 0.0f;   // fused ReLU
    o.y = oy > 0.0f ? oy : 0.0f;
    long long bits;
    memcpy(&bits, &o, 8);
    long long* dst = reinterpret_cast<long long*>(out + (size_t)node * HIDDEN) + lane;
    __builtin_nontemporal_store(bits, dst);
}

// fp32 fallback aggregate (used only if ws_size can't hold the bf16 copy).
__global__ void aggregate_f32_k(const float* __restrict__ x,
                                const int* __restrict__ offsets,
                                const int* __restrict__ counts,
                                const int2* __restrict__ te_sorted,
                                float* __restrict__ out,
                                int n_nodes) {
    int gtid = blockIdx.x * blockDim.x + threadIdx.x;
    int node = gtid >> 6;
    int lane = threadIdx.x & 63;
    if (node >= n_nodes) return;
    int beg = offsets[node];
    int deg = counts[node];
    int end = beg + deg;
    float accx = 0.0f, accy = 0.0f, ssum = 0.0f;
    int j = beg;
    for (; j + 4 <= end; j += 4) {
        int2 e0 = te_sorted[j + 0];
        int2 e1 = te_sorted[j + 1];
        int2 e2 = te_sorted[j + 2];
        int2 e3 = te_sorted[j + 3];
        float2 v0 = reinterpret_cast<const float2*>(x + (size_t)e0.x * HIDDEN)[lane];
        float2 v1 = reinterpret_cast<const float2*>(x + (size_t)e1.x * HIDDEN)[lane];
        float2 v2 = reinterpret_cast<const float2*>(x + (size_t)e2.x * HIDDEN)[lane];
        float2 v3 = reinterpret_cast<const float2*>(x + (size_t)e3.x * HIDDEN)[lane];
        float a0 = __int_as_float(e0.y), a1 = __int_as_float(e1.y);
        float a2 = __int_as_float(e2.y), a3 = __int_as_float(e3.y);
        ssum += (a0 + a1) + (a2 + a3);
        accx += a0 * v0.x + a1 * v1.x + a2 * v2.x + a3 * v3.x;
        accy += a0 * v0.y + a1 * v1.y + a2 * v2.y + a3 * v3.y;
    }
    for (; j < end; ++j) {
        int2 e0 = te_sorted[j];
        float2 v0 = reinterpret_cast<const float2*>(x + (size_t)e0.x * HIDDEN)[lane];
        float a0 = __int_as_float(e0.y);
        ssum += a0; accx += a0 * v0.x; accy += a0 * v0.y;
    }
    float inv = (deg > 0) ? (1.0f / ssum) : 0.0f;
    float ox = accx * inv, oy = accy * inv;
    float2 o;
    o.x = ox > 0.0f ? ox : 0.0f;
    o.y = oy > 0.0f ? oy : 0.0f;
    long long bits;
    memcpy(&bits, &o, 8);
    long long* dst = reinterpret_cast<long long*>(out + (size_t)node * HIDDEN) + lane;
    __builtin_nontemporal_store(bits, dst);
}

extern "C" void kernel_launch(void* const* d_in, const int* in_sizes, int n_in,
                              void* d_out, int out_size, void* d_ws, size_t ws_size,
                              hipStream_t stream) {
    const float* x   = (const float*)d_in[0];
    const float* w_i = (const float*)d_in[1];
    const float* w_j = (const float*)d_in[2];
    const int*   h   = (const int*)d_in[3];
    const int*   t   = (const int*)d_in[4];
    float* out = (float*)d_out;

    const int n_nodes = in_sizes[0] / HIDDEN;
    const int n_edges = in_sizes[3];
    const long long n_x = (long long)n_nodes * HIDDEN;
    const int nchunks = (n_nodes + SCAN_CHUNK - 1) / SCAN_CHUNK;  // <= 256

    // Workspace layout:
    // s_i[N] f | s_j[N] f | counts[N] i | cursors[N] i | offsets[N] i |
    // blockSums[256] i | te_sorted[E] int2 | x_bf16[N*128] u16
    float* s_i       = (float*)d_ws;
    float* s_j       = s_i + n_nodes;
    int*   counts    = (int*)(s_j + n_nodes);
    int*   cursors   = counts + n_nodes;       // adjacent -> single memset
    int*   offsets   = cursors + n_nodes;
    int*   blockSums = offsets + n_nodes;
    int2*  te_sorted = reinterpret_cast<int2*>(blockSums + 256);
    unsigned short* x_bf16 = reinterpret_cast<unsigned short*>(te_sorted + n_edges);

    size_t need_bf16 = (size_t)((char*)(x_bf16 + n_x) - (char*)d_ws);
    const bool use_bf16 = ws_size >= need_bf16;

    hipMemsetAsync(counts, 0, (size_t)(2 * n_nodes) * sizeof(int), stream);

    if (use_bf16) {  // Stage 0: bf16 copy of x for the aggregate gathers.
        int blocks = (int)((n_x / 4 + 255) / 256);
        cvt_bf16_k<<<blocks, 256, 0, stream>>>(x, x_bf16, n_x);
    }
    {   // Stage 1: wave per node.
        int blocks = (n_nodes * 64 + 255) / 256;
        node_scores_k<<<blocks, 256, 0, stream>>>(x, w_i, w_j, s_i, s_j, n_nodes);
    }
    {   // Stage 2: histogram.
        int blocks = (n_edges + 255) / 256;
        hist_k<<<blocks, 256, 0, stream>>>(h, counts, n_edges);
    }
    {   // Stage 3: exclusive scan counts -> offsets.
        scan1_k<<<nchunks, 256, 0, stream>>>(counts, offsets, blockSums, n_nodes);
        scan2_k<<<1, 256, 0, stream>>>(blockSums, nchunks);
        scan3_k<<<nchunks, 256, 0, stream>>>(offsets, blockSums, n_nodes);
    }
    {   // Stage 4: scatter into CSR order.
        int blocks = (n_edges + 255) / 256;
        scatter_k<<<blocks, 256, 0, stream>>>(s_i, s_j, h, t, offsets, cursors,
                                              te_sorted, n_edges);
    }
    {   // Stage 5: single-pass aggregate + ReLU, wave per node.
        int blocks = (n_nodes * 64 + 255) / 256;
        if (use_bf16) {
            aggregate_bf16_k<<<blocks, 256, 0, stream>>>(
                x_bf16, offsets, counts,
                reinterpret_cast<const long long*>(te_sorted), out, n_nodes);
        } else {
            aggregate_f32_k<<<blocks, 256, 0, stream>>>(x, offsets, counts,
                                                        te_sorted, out, n_nodes);
        }
    }
}